// Round 1
// baseline (141.084 us; speedup 1.0000x reference)
//
#include <hip/hip_runtime.h>
#include <math.h>

#define N 4096
#define D 768
#define MARGIN 1.0f
#define NBLK 576   // 512 full 128x128 tiles + 16 tiles split into 4x(128x32)
#define NKT 24     // K-steps of BK=32

typedef _Float16 half8 __attribute__((ext_vector_type(8)));
typedef _Float16 half4 __attribute__((ext_vector_type(4)));
typedef float f32x4 __attribute__((ext_vector_type(4)));

__device__ __forceinline__ void gl2lds16(const void* g, void* l) {
    __builtin_amdgcn_global_load_lds((const __attribute__((address_space(1))) void*)g,
                                     (__attribute__((address_space(3))) void*)l, 16, 0, 0);
}

// counted vmcnt wait (literal must be compile-time)
template<int Nv>
__device__ __forceinline__ void wait_vm() {
    if constexpr (Nv == 0)      asm volatile("s_waitcnt vmcnt(0)" ::: "memory");
    else if constexpr (Nv == 3) asm volatile("s_waitcnt vmcnt(3)" ::: "memory");
    else                        asm volatile("s_waitcnt vmcnt(4)" ::: "memory");
}

// ---------------- Kernel 1: row L2-normalize (wave-per-row) + init ----------
__global__ __launch_bounds__(256) void normalize_kernel(const float* __restrict__ x,
                                                        _Float16* __restrict__ e,
                                                        float* __restrict__ sq,
                                                        unsigned* __restrict__ ap_bits,
                                                        unsigned* __restrict__ an_bits,
                                                        unsigned* __restrict__ counter) {
    const int tid = threadIdx.x;
    const int wave = tid >> 6, lane = tid & 63;
    const int row = blockIdx.x * 4 + wave;

    const float4* xr = (const float4*)(x + (size_t)row * D);   // 192 float4/row
    float4 f0 = xr[lane];
    float4 f1 = xr[lane + 64];
    float4 f2 = xr[lane + 128];

    float s = f0.x*f0.x + f0.y*f0.y + f0.z*f0.z + f0.w*f0.w
            + f1.x*f1.x + f1.y*f1.y + f1.z*f1.z + f1.w*f1.w
            + f2.x*f2.x + f2.y*f2.y + f2.z*f2.z + f2.w*f2.w;
    #pragma unroll
    for (int off = 1; off < 64; off <<= 1) s += __shfl_xor(s, off, 64);

    float scale = 1.0f / fmaxf(sqrtf(s), 1e-12f);

    half4* er = (half4*)(e + (size_t)row * D);
    half4 h0 = { (_Float16)(f0.x*scale), (_Float16)(f0.y*scale), (_Float16)(f0.z*scale), (_Float16)(f0.w*scale) };
    half4 h1 = { (_Float16)(f1.x*scale), (_Float16)(f1.y*scale), (_Float16)(f1.z*scale), (_Float16)(f1.w*scale) };
    half4 h2 = { (_Float16)(f2.x*scale), (_Float16)(f2.y*scale), (_Float16)(f2.z*scale), (_Float16)(f2.w*scale) };
    er[lane]       = h0;
    er[lane + 64]  = h1;
    er[lane + 128] = h2;

    if (lane == 0) {
        sq[row] = s * scale * scale;
        ap_bits[row] = 0u;                 // float 0.0  (max init)
        an_bits[row] = 0x7f800000u;        // +inf       (min init)
    }
    if (blockIdx.x == 0 && tid == 0) *counter = 0u;
}

// ---------------- staging: one K-step (BK=32) of A+B into buffer Sb --------
// loads/stage/wave: BROWS==128 -> 4, BROWS==32 -> 3 (waves 2-3 duplicate
// waves 0-1's B granules: same bytes to same LDS addrs, benign; keeps the
// per-wave vmcnt count uniform for the counted wait).
template<int BROWS>
__device__ __forceinline__ void stage_tile(const _Float16* __restrict__ e,
                                           int i0, int jbase, int k0,
                                           unsigned short* Sb, int tid, int w) {
    #pragma unroll
    for (int p = 0; p < 2; ++p) {
        int s  = p * 256 + tid;
        int r  = s >> 2;
        int kg = (s & 3) ^ ((r >> 1) & 3);
        gl2lds16(e + (size_t)(i0 + r) * D + k0 + kg * 8,
                 (char*)Sb + (p * 256 + w * 64) * 16);
    }
    if constexpr (BROWS == 128) {
        #pragma unroll
        for (int p = 0; p < 2; ++p) {
            int s  = p * 256 + tid;
            int r  = s >> 2;
            int kg = (s & 3) ^ ((r >> 1) & 3);
            gl2lds16(e + (size_t)(jbase + r) * D + k0 + kg * 8,
                     (char*)Sb + 8192 + (p * 256 + w * 64) * 16);
        }
    } else {
        int s  = tid & 127;                // waves 2,3 mirror waves 0,1
        int r  = s >> 2;
        int kg = (s & 3) ^ ((r >> 1) & 3);
        gl2lds16(e + (size_t)(jbase + r) * D + k0 + kg * 8,
                 (char*)Sb + 8192 + ((w & 1) * 64) * 16);
    }
}

// ---------------- templated tile worker: 3-buffer depth-2 pipeline ---------
// LDS per buffer: A = 128x32 halves (8KB, XOR-swizzled) | B = 8KB. 3 bufs.
template<int MTN, int NTN, int BROWS>
__device__ __forceinline__ void tile_work(const _Float16* __restrict__ e,
                                          const float* __restrict__ sq,
                                          const int* __restrict__ labels,
                                          unsigned* __restrict__ ap_bits,
                                          unsigned* __restrict__ an_bits,
                                          unsigned short* S,
                                          int i0, int jbase,
                                          int wi, int wjL,
                                          int tid, int w, int lane, bool diag) {
    const int ln15 = lane & 15;
    const int lq   = lane >> 4;       // 0..3
    constexpr int LPS = (BROWS == 128) ? 4 : 3;   // loads per stage per wave

    f32x4 acc[MTN][NTN] = {};

    // prologue: stage steps 0 and 1 (depth-2 in flight)
    stage_tile<BROWS>(e, i0, jbase, 0,  S,        tid, w);
    stage_tile<BROWS>(e, i0, jbase, 32, S + 8192, tid, w);

    int cur = 0, nx2 = 2;
    for (int kt = 0; kt < NKT; ++kt) {
        // wait for step-kt's stage only (step kt+1 stays in flight); last
        // iter has only its own stage outstanding -> drain.
        if (kt < NKT - 1) wait_vm<LPS>(); else wait_vm<0>();
        __builtin_amdgcn_s_barrier();
        __builtin_amdgcn_sched_barrier(0);

        // issue step kt+2 into the buffer read at iter kt-1 (all waves are
        // past barrier kt, so their iter-(kt-1) ds_reads have completed).
        if (kt + 2 < NKT)
            stage_tile<BROWS>(e, i0, jbase, (kt + 2) * 32, S + nx2 * 8192, tid, w);
        __builtin_amdgcn_sched_barrier(0);

        const unsigned short* Sb = S + cur * 8192;
        half8 af[MTN], bf[NTN];
        #pragma unroll
        for (int mt = 0; mt < MTN; ++mt) {
            int r  = wi + mt * 16 + ln15;
            int kx = lq ^ ((r >> 1) & 3);
            af[mt] = *(const half8*)&Sb[r * 32 + kx * 8];
        }
        #pragma unroll
        for (int nt = 0; nt < NTN; ++nt) {
            int r  = wjL + nt * 16 + ln15;
            int kx = lq ^ ((r >> 1) & 3);
            bf[nt] = *(const half8*)&Sb[4096 + r * 32 + kx * 8];
        }
        __builtin_amdgcn_s_setprio(1);
        #pragma unroll
        for (int mt = 0; mt < MTN; ++mt)
            #pragma unroll
            for (int nt = 0; nt < NTN; ++nt)
                acc[mt][nt] = __builtin_amdgcn_mfma_f32_16x16x32_f16(af[mt], bf[nt], acc[mt][nt], 0, 0, 0);
        __builtin_amdgcn_s_setprio(0);

        cur = (cur == 2) ? 0 : cur + 1;
        nx2 = (nx2 == 2) ? 0 : nx2 + 1;
    }

    // ---------------- epilogue: dist + dual-sided batch-hard mining ----------
    float sqi[MTN][4]; int labi[MTN][4];
    #pragma unroll
    for (int mt = 0; mt < MTN; ++mt)
        #pragma unroll
        for (int rg = 0; rg < 4; ++rg) {
            int i = i0 + wi + mt * 16 + lq * 4 + rg;
            sqi[mt][rg] = sq[i];
            labi[mt][rg] = labels[i];
        }
    float sqj[NTN]; int labj[NTN];
    #pragma unroll
    for (int nt = 0; nt < NTN; ++nt) {
        int j = jbase + wjL + nt * 16 + ln15;
        sqj[nt] = sq[j];
        labj[nt] = labels[j];
    }

    float api[MTN][4], ani[MTN][4], apj[NTN], anj[NTN];
    #pragma unroll
    for (int mt = 0; mt < MTN; ++mt)
        #pragma unroll
        for (int rg = 0; rg < 4; ++rg) { api[mt][rg] = -INFINITY; ani[mt][rg] = INFINITY; }
    #pragma unroll
    for (int nt = 0; nt < NTN; ++nt) { apj[nt] = -INFINITY; anj[nt] = INFINITY; }

    #pragma unroll
    for (int nt = 0; nt < NTN; ++nt) {
        int j = jbase + wjL + nt * 16 + ln15;
        #pragma unroll
        for (int mt = 0; mt < MTN; ++mt)
            #pragma unroll
            for (int rg = 0; rg < 4; ++rg) {
                int i = i0 + wi + mt * 16 + lq * 4 + rg;
                float d2 = sqi[mt][rg] + sqj[nt] - 2.0f * acc[mt][nt][rg];
                float dist = sqrtf(fmaxf(d2, 0.0f) + 1e-12f);
                if (labi[mt][rg] == labj[nt]) {
                    if (i != j) {
                        api[mt][rg] = fmaxf(api[mt][rg], dist);
                        apj[nt]     = fmaxf(apj[nt], dist);
                    }
                } else {
                    ani[mt][rg] = fminf(ani[mt][rg], dist);
                    anj[nt]     = fminf(anj[nt], dist);
                }
            }
    }

    // i-side reduce over the 16 ln15-lanes
    #pragma unroll
    for (int mt = 0; mt < MTN; ++mt)
        #pragma unroll
        for (int rg = 0; rg < 4; ++rg) {
            float a_ = api[mt][rg], n_ = ani[mt][rg];
            #pragma unroll
            for (int off = 1; off < 16; off <<= 1) {
                a_ = fmaxf(a_, __shfl_xor(a_, off, 64));
                n_ = fminf(n_, __shfl_xor(n_, off, 64));
            }
            if (ln15 == 0) {
                int i = i0 + wi + mt * 16 + lq * 4 + rg;
                if (a_ > -1.0e37f) atomicMax(&ap_bits[i], __float_as_uint(a_));
                if (n_ <  1.0e37f) atomicMin(&an_bits[i], __float_as_uint(n_));
            }
        }

    // j-side reduce over the 4 lq-quads (skip on diagonal tiles — i-side covers them)
    if (!diag) {
        #pragma unroll
        for (int nt = 0; nt < NTN; ++nt) {
            float a_ = apj[nt], n_ = anj[nt];
            #pragma unroll
            for (int off = 16; off < 64; off <<= 1) {
                a_ = fmaxf(a_, __shfl_xor(a_, off, 64));
                n_ = fminf(n_, __shfl_xor(n_, off, 64));
            }
            if (lq == 0) {
                int j = jbase + wjL + nt * 16 + ln15;
                if (a_ > -1.0e37f) atomicMax(&ap_bits[j], __float_as_uint(a_));
                if (n_ <  1.0e37f) atomicMin(&an_bits[j], __float_as_uint(n_));
            }
        }
    }
}

// ------- Kernel 2: MFMA Gram + mining (balanced triangular) + finalize ------
__global__ __launch_bounds__(256) void mine_kernel(const _Float16* __restrict__ e,
                                                   const float* __restrict__ sq,
                                                   const int* __restrict__ labels,
                                                   unsigned* __restrict__ ap_bits,
                                                   unsigned* __restrict__ an_bits,
                                                   unsigned* __restrict__ counter,
                                                   float* __restrict__ out) {
    __shared__ unsigned short S[3 * 8192];  // 3 buffers x (A 8KB | B 8KB) = 48KB

    const int tid  = threadIdx.x;
    const int w    = tid >> 6;
    const int lane = tid & 63;

    // XCD-aware bijective swizzle (576 = 8*72): each XCD gets 72 consecutive
    // work items -> ~3 shared A-panels (0.6MB) stay L2-resident per XCD.
    const int b = (blockIdx.x % 8) * 72 + (blockIdx.x / 8);

    // schedule: work 0..511 -> full tiles; 512..575 -> tiles 512..527 split
    // into 4 j-quarters of 32 columns each.
    int t, jlo, small;
    if (b < 512) { t = b; jlo = 0; small = 0; }
    else { int s2 = b - 512; t = 512 + (s2 >> 2); jlo = (s2 & 3) * 32; small = 1; }

    int bi = 0, rem = t;
    while (rem >= 32 - bi) { rem -= 32 - bi; ++bi; }
    const int bj = bi + rem;
    const int i0 = bi * 128, j0 = bj * 128;

    if (!small)
        tile_work<4, 4, 128>(e, sq, labels, ap_bits, an_bits, S, i0, j0,
                             (w & 1) * 64, (w >> 1) * 64, tid, w, lane, bi == bj);
    else
        tile_work<2, 2, 32>(e, sq, labels, ap_bits, an_bits, S, i0, j0 + jlo,
                            w * 32, 0, tid, w, lane, bi == bj);

    // ---------------- last-block finalize (scoped sync — no global cache nuke) ----
    __shared__ unsigned lastFlag;
    __syncthreads();   // each wave's s_waitcnt vmcnt(0) before barrier drains its atomics
    if (tid == 0) {
        __builtin_amdgcn_fence(__ATOMIC_RELEASE, "agent");   // wbl2 only; ~no dirty data
        lastFlag = (atomicAdd(counter, 1u) == NBLK - 1) ? 1u : 0u;
    }
    __syncthreads();
    if (!lastFlag) return;
    __builtin_amdgcn_fence(__ATOMIC_ACQUIRE, "agent");       // one block: inv L1/L2 once

    __shared__ int cnt[4];
    __shared__ float red[8];
    if (tid < 4) cnt[tid] = 0;
    __syncthreads();
    int local[4] = {0, 0, 0, 0};
    for (int i = tid; i < N; i += 256) local[labels[i] & 3]++;
    #pragma unroll
    for (int c = 0; c < 4; c++) atomicAdd(&cnt[c], local[c]);
    __syncthreads();

    float sum = 0.f, nv = 0.f;
    for (int i = tid; i < N; i += 256) {
        int l = labels[i] & 3;
        if (cnt[l] >= 2) {
            nv += 1.f;
            float apv = __uint_as_float(ap_bits[i]);   // plain loads: caches inv'd above
            float anv = __uint_as_float(an_bits[i]);
            if (anv < 3.0e38f) sum += fmaxf(apv - anv + MARGIN, 0.f);
        }
    }

    #pragma unroll
    for (int off = 32; off; off >>= 1) {
        sum += __shfl_down(sum, off, 64);
        nv  += __shfl_down(nv,  off, 64);
    }
    if ((tid & 63) == 0) { red[tid >> 6] = sum; red[4 + (tid >> 6)] = nv; }
    __syncthreads();
    if (tid == 0) {
        float s = red[0] + red[1] + red[2] + red[3];
        float n = red[4] + red[5] + red[6] + red[7];
        out[0] = s / fmaxf(n, 1.f);
    }
}

// ---------------- Launch ----------------
extern "C" void kernel_launch(void* const* d_in, const int* in_sizes, int n_in,
                              void* d_out, int out_size, void* d_ws, size_t ws_size,
                              hipStream_t stream) {
    const float* x = (const float*)d_in[0];
    const int* labels = (const int*)d_in[1];
    float* out = (float*)d_out;

    _Float16* e = (_Float16*)d_ws;
    float* sq = (float*)(e + (size_t)N * D);
    unsigned* ap_bits = (unsigned*)(sq + N);
    unsigned* an_bits = ap_bits + N;
    unsigned* counter = an_bits + N;

    normalize_kernel<<<N / 4, 256, 0, stream>>>(x, e, sq, ap_bits, an_bits, counter);
    mine_kernel<<<NBLK, 256, 0, stream>>>(e, sq, labels, ap_bits, an_bits, counter, out);
}

// Round 2
// 122.701 us; speedup vs baseline: 1.1498x; 1.1498x over previous
//
#include <hip/hip_runtime.h>
#include <math.h>

#define N 4096
#define D 768
#define MARGIN 1.0f
#define NBLK 576   // 512 full 128x128 tiles + 16 tiles split into 4x(128x32)
#define NKT 24     // K-steps of BK=32
#define NSLOT 32   // scratch slots per row (one per full-tile contributor)

typedef _Float16 half8 __attribute__((ext_vector_type(8)));
typedef _Float16 half4 __attribute__((ext_vector_type(4)));
typedef float f32x4 __attribute__((ext_vector_type(4)));

__device__ __forceinline__ void gl2lds16(const void* g, void* l) {
    __builtin_amdgcn_global_load_lds((const __attribute__((address_space(1))) void*)g,
                                     (__attribute__((address_space(3))) void*)l, 16, 0, 0);
}

// counted vmcnt wait (literal must be compile-time)
template<int Nv>
__device__ __forceinline__ void wait_vm() {
    if constexpr (Nv == 0)      asm volatile("s_waitcnt vmcnt(0)" ::: "memory");
    else if constexpr (Nv == 3) asm volatile("s_waitcnt vmcnt(3)" ::: "memory");
    else                        asm volatile("s_waitcnt vmcnt(4)" ::: "memory");
}

// ---------------- Kernel 1: row L2-normalize (wave-per-row) + init ----------
__global__ __launch_bounds__(256) void normalize_kernel(const float* __restrict__ x,
                                                        _Float16* __restrict__ e,
                                                        float* __restrict__ sq,
                                                        unsigned* __restrict__ ap_bits,
                                                        unsigned* __restrict__ an_bits,
                                                        float* __restrict__ ap_part,
                                                        float* __restrict__ an_part,
                                                        float* __restrict__ acc,
                                                        unsigned* __restrict__ counter) {
    const int tid = threadIdx.x;
    const int wave = tid >> 6, lane = tid & 63;
    const int row = blockIdx.x * 4 + wave;

    const float4* xr = (const float4*)(x + (size_t)row * D);   // 192 float4/row
    float4 f0 = xr[lane];
    float4 f1 = xr[lane + 64];
    float4 f2 = xr[lane + 128];

    float s = f0.x*f0.x + f0.y*f0.y + f0.z*f0.z + f0.w*f0.w
            + f1.x*f1.x + f1.y*f1.y + f1.z*f1.z + f1.w*f1.w
            + f2.x*f2.x + f2.y*f2.y + f2.z*f2.z + f2.w*f2.w;
    #pragma unroll
    for (int off = 1; off < 64; off <<= 1) s += __shfl_xor(s, off, 64);

    float scale = 1.0f / fmaxf(sqrtf(s), 1e-12f);

    half4* er = (half4*)(e + (size_t)row * D);
    half4 h0 = { (_Float16)(f0.x*scale), (_Float16)(f0.y*scale), (_Float16)(f0.z*scale), (_Float16)(f0.w*scale) };
    half4 h1 = { (_Float16)(f1.x*scale), (_Float16)(f1.y*scale), (_Float16)(f1.z*scale), (_Float16)(f1.w*scale) };
    half4 h2 = { (_Float16)(f2.x*scale), (_Float16)(f2.y*scale), (_Float16)(f2.z*scale), (_Float16)(f2.w*scale) };
    er[lane]       = h0;
    er[lane + 64]  = h1;
    er[lane + 128] = h2;

    if (lane == 0) {
        sq[row] = s * scale * scale;
        ap_bits[row] = 0u;                 // float 0.0  (max init)
        an_bits[row] = 0x7f800000u;        // +inf       (min init)
    }
    // scratch init: 1024 blocks x 256 threads = 262144 = 2 x (NSLOT*N)
    int g = blockIdx.x * 256 + tid;
    if (g < NSLOT * N) ap_part[g] = 0.0f;
    else               an_part[g - NSLOT * N] = INFINITY;

    if (blockIdx.x == 0 && tid == 0) { acc[0] = 0.f; acc[1] = 0.f; *counter = 0u; }
}

// ---------------- staging: one K-step (BK=32) of A+B into buffer Sb --------
template<int BROWS>
__device__ __forceinline__ void stage_tile(const _Float16* __restrict__ e,
                                           int i0, int jbase, int k0,
                                           unsigned short* Sb, int tid, int w) {
    #pragma unroll
    for (int p = 0; p < 2; ++p) {
        int s  = p * 256 + tid;
        int r  = s >> 2;
        int kg = (s & 3) ^ ((r >> 1) & 3);
        gl2lds16(e + (size_t)(i0 + r) * D + k0 + kg * 8,
                 (char*)Sb + (p * 256 + w * 64) * 16);
    }
    if constexpr (BROWS == 128) {
        #pragma unroll
        for (int p = 0; p < 2; ++p) {
            int s  = p * 256 + tid;
            int r  = s >> 2;
            int kg = (s & 3) ^ ((r >> 1) & 3);
            gl2lds16(e + (size_t)(jbase + r) * D + k0 + kg * 8,
                     (char*)Sb + 8192 + (p * 256 + w * 64) * 16);
        }
    } else {  // 32 rows; waves 2,3 mirror waves 0,1 (same bytes->same addr, benign)
        int s  = tid & 127;
        int r  = s >> 2;
        int kg = (s & 3) ^ ((r >> 1) & 3);
        gl2lds16(e + (size_t)(jbase + r) * D + k0 + kg * 8,
                 (char*)Sb + 8192 + ((w & 1) * 64) * 16);
    }
}

// ---------------- templated tile worker: 3-buffer depth-2 pipeline ---------
// SCR=true: full tiles write per-slot scratch (no atomics, LDS wave-merge).
// SCR=false: split tiles use device atomics on ap_bits/an_bits.
template<int MTN, int NTN, int BROWS, bool SCR>
__device__ __forceinline__ void tile_work(const _Float16* __restrict__ e,
                                          const float* __restrict__ sq,
                                          const int* __restrict__ labels,
                                          unsigned* __restrict__ ap_bits,
                                          unsigned* __restrict__ an_bits,
                                          float* __restrict__ ap_part,
                                          float* __restrict__ an_part,
                                          unsigned short* S,
                                          int i0, int jbase,
                                          int slot_i, int slot_j,
                                          int wi, int wjL,
                                          int tid, int w, int lane, bool diag) {
    const int ln15 = lane & 15;
    const int lq   = lane >> 4;       // 0..3
    constexpr int LPS = (BROWS == 128) ? 4 : 3;   // loads per stage per wave

    f32x4 acc[MTN][NTN] = {};

    // prologue: stage steps 0 and 1 (depth-2 in flight)
    stage_tile<BROWS>(e, i0, jbase, 0,  S,        tid, w);
    stage_tile<BROWS>(e, i0, jbase, 32, S + 8192, tid, w);

    int cur = 0, nx2 = 2;
    for (int kt = 0; kt < NKT; ++kt) {
        if (kt < NKT - 1) wait_vm<LPS>(); else wait_vm<0>();
        __builtin_amdgcn_s_barrier();
        __builtin_amdgcn_sched_barrier(0);

        if (kt + 2 < NKT)
            stage_tile<BROWS>(e, i0, jbase, (kt + 2) * 32, S + nx2 * 8192, tid, w);
        __builtin_amdgcn_sched_barrier(0);

        const unsigned short* Sb = S + cur * 8192;
        half8 af[MTN], bf[NTN];
        #pragma unroll
        for (int mt = 0; mt < MTN; ++mt) {
            int r  = wi + mt * 16 + ln15;
            int kx = lq ^ ((r >> 1) & 3);
            af[mt] = *(const half8*)&Sb[r * 32 + kx * 8];
        }
        #pragma unroll
        for (int nt = 0; nt < NTN; ++nt) {
            int r  = wjL + nt * 16 + ln15;
            int kx = lq ^ ((r >> 1) & 3);
            bf[nt] = *(const half8*)&Sb[4096 + r * 32 + kx * 8];
        }
        __builtin_amdgcn_s_setprio(1);
        #pragma unroll
        for (int mt = 0; mt < MTN; ++mt)
            #pragma unroll
            for (int nt = 0; nt < NTN; ++nt)
                acc[mt][nt] = __builtin_amdgcn_mfma_f32_16x16x32_f16(af[mt], bf[nt], acc[mt][nt], 0, 0, 0);
        __builtin_amdgcn_s_setprio(0);

        cur = (cur == 2) ? 0 : cur + 1;
        nx2 = (nx2 == 2) ? 0 : nx2 + 1;
    }

    // ---------------- epilogue: dist + dual-sided batch-hard mining ----------
    float sqi[MTN][4]; int labi[MTN][4];
    #pragma unroll
    for (int mt = 0; mt < MTN; ++mt)
        #pragma unroll
        for (int rg = 0; rg < 4; ++rg) {
            int i = i0 + wi + mt * 16 + lq * 4 + rg;
            sqi[mt][rg] = sq[i];
            labi[mt][rg] = labels[i];
        }
    float sqj[NTN]; int labj[NTN];
    #pragma unroll
    for (int nt = 0; nt < NTN; ++nt) {
        int j = jbase + wjL + nt * 16 + ln15;
        sqj[nt] = sq[j];
        labj[nt] = labels[j];
    }

    float api[MTN][4], ani[MTN][4], apj[NTN], anj[NTN];
    #pragma unroll
    for (int mt = 0; mt < MTN; ++mt)
        #pragma unroll
        for (int rg = 0; rg < 4; ++rg) { api[mt][rg] = -INFINITY; ani[mt][rg] = INFINITY; }
    #pragma unroll
    for (int nt = 0; nt < NTN; ++nt) { apj[nt] = -INFINITY; anj[nt] = INFINITY; }

    #pragma unroll
    for (int nt = 0; nt < NTN; ++nt) {
        int j = jbase + wjL + nt * 16 + ln15;
        #pragma unroll
        for (int mt = 0; mt < MTN; ++mt)
            #pragma unroll
            for (int rg = 0; rg < 4; ++rg) {
                int i = i0 + wi + mt * 16 + lq * 4 + rg;
                float d2 = sqi[mt][rg] + sqj[nt] - 2.0f * acc[mt][nt][rg];
                float dist = sqrtf(fmaxf(d2, 0.0f) + 1e-12f);
                if (labi[mt][rg] == labj[nt]) {
                    if (i != j) {
                        api[mt][rg] = fmaxf(api[mt][rg], dist);
                        apj[nt]     = fmaxf(apj[nt], dist);
                    }
                } else {
                    ani[mt][rg] = fminf(ani[mt][rg], dist);
                    anj[nt]     = fminf(anj[nt], dist);
                }
            }
    }

    if constexpr (SCR) {
        // ---- atomic-free path: LDS wave-merge, then one store per (row,slot)
        float* F = (float*)S;   // 4 waves x 64 entries x 2 floats = 2KB
        // i-side: reduce over the 16 ln15-lanes, stage to LDS
        #pragma unroll
        for (int mt = 0; mt < MTN; ++mt)
            #pragma unroll
            for (int rg = 0; rg < 4; ++rg) {
                float a_ = api[mt][rg], n_ = ani[mt][rg];
                #pragma unroll
                for (int off = 1; off < 16; off <<= 1) {
                    a_ = fmaxf(a_, __shfl_xor(a_, off, 64));
                    n_ = fminf(n_, __shfl_xor(n_, off, 64));
                }
                if (ln15 == 0) {
                    int rl = mt * 16 + lq * 4 + rg;          // 0..63
                    F[w * 128 + rl * 2]     = a_;
                    F[w * 128 + rl * 2 + 1] = n_;
                }
            }
        __syncthreads();
        if (tid < 128) {  // merge duplicate waves {0,2}->rows wi=0, {1,3}->wi=64
            int half = tid >> 6, rl = tid & 63;
            int wA = half, wB = half + 2;
            float a_ = fmaxf(F[wA * 128 + rl * 2],     F[wB * 128 + rl * 2]);
            float n_ = fminf(F[wA * 128 + rl * 2 + 1], F[wB * 128 + rl * 2 + 1]);
            int row = i0 + half * 64 + rl;
            ap_part[slot_i * N + row] = a_;
            an_part[slot_i * N + row] = n_;
        }
        // j-side (skip on diagonal tiles — i-side covers them)
        if (!diag) {
            __syncthreads();
            #pragma unroll
            for (int nt = 0; nt < NTN; ++nt) {
                float a_ = apj[nt], n_ = anj[nt];
                #pragma unroll
                for (int off = 16; off < 64; off <<= 1) {
                    a_ = fmaxf(a_, __shfl_xor(a_, off, 64));
                    n_ = fminf(n_, __shfl_xor(n_, off, 64));
                }
                if (lq == 0) {
                    int jl = nt * 16 + ln15;                 // 0..63
                    F[w * 128 + jl * 2]     = a_;
                    F[w * 128 + jl * 2 + 1] = n_;
                }
            }
            __syncthreads();
            if (tid < 128) {  // merge {0,1}->cols wjL=0, {2,3}->wjL=64
                int half = tid >> 6, jl = tid & 63;
                int wA = half * 2, wB = half * 2 + 1;
                float a_ = fmaxf(F[wA * 128 + jl * 2],     F[wB * 128 + jl * 2]);
                float n_ = fminf(F[wA * 128 + jl * 2 + 1], F[wB * 128 + jl * 2 + 1]);
                int col = jbase + half * 64 + jl;
                ap_part[slot_j * N + col] = a_;
                an_part[slot_j * N + col] = n_;
            }
        }
    } else {
        // ---- split-tile path: device atomics (only 64 small sub-blocks)
        #pragma unroll
        for (int mt = 0; mt < MTN; ++mt)
            #pragma unroll
            for (int rg = 0; rg < 4; ++rg) {
                float a_ = api[mt][rg], n_ = ani[mt][rg];
                #pragma unroll
                for (int off = 1; off < 16; off <<= 1) {
                    a_ = fmaxf(a_, __shfl_xor(a_, off, 64));
                    n_ = fminf(n_, __shfl_xor(n_, off, 64));
                }
                if (ln15 == 0) {
                    int i = i0 + wi + mt * 16 + lq * 4 + rg;
                    if (a_ > -1.0e37f) atomicMax(&ap_bits[i], __float_as_uint(a_));
                    if (n_ <  1.0e37f) atomicMin(&an_bits[i], __float_as_uint(n_));
                }
            }
        if (!diag) {
            #pragma unroll
            for (int nt = 0; nt < NTN; ++nt) {
                float a_ = apj[nt], n_ = anj[nt];
                #pragma unroll
                for (int off = 16; off < 64; off <<= 1) {
                    a_ = fmaxf(a_, __shfl_xor(a_, off, 64));
                    n_ = fminf(n_, __shfl_xor(n_, off, 64));
                }
                if (lq == 0) {
                    int j = jbase + wjL + nt * 16 + ln15;
                    if (a_ > -1.0e37f) atomicMax(&ap_bits[j], __float_as_uint(a_));
                    if (n_ <  1.0e37f) atomicMin(&an_bits[j], __float_as_uint(n_));
                }
            }
        }
    }
}

// ------- Kernel 2: MFMA Gram + mining (balanced triangular) -----------------
__global__ __launch_bounds__(256) void mine_kernel(const _Float16* __restrict__ e,
                                                   const float* __restrict__ sq,
                                                   const int* __restrict__ labels,
                                                   unsigned* __restrict__ ap_bits,
                                                   unsigned* __restrict__ an_bits,
                                                   float* __restrict__ ap_part,
                                                   float* __restrict__ an_part) {
    __shared__ unsigned short S[3 * 8192];  // 3 buffers x (A 8KB | B 8KB) = 48KB

    const int tid  = threadIdx.x;
    const int w    = tid >> 6;
    const int lane = tid & 63;

    // XCD-aware bijective swizzle (576 = 8*72)
    const int b = (blockIdx.x % 8) * 72 + (blockIdx.x / 8);

    int t, jlo, small;
    if (b < 512) { t = b; jlo = 0; small = 0; }
    else { int s2 = b - 512; t = 512 + (s2 >> 2); jlo = (s2 & 3) * 32; small = 1; }

    int bi = 0, rem = t;
    while (rem >= 32 - bi) { rem -= 32 - bi; ++bi; }
    const int bj = bi + rem;
    const int i0 = bi * 128, j0 = bj * 128;

    if (!small)
        tile_work<4, 4, 128, true>(e, sq, labels, ap_bits, an_bits, ap_part, an_part, S,
                                   i0, j0, /*slot_i=*/bj, /*slot_j=*/bi,
                                   (w & 1) * 64, (w >> 1) * 64, tid, w, lane, bi == bj);
    else
        tile_work<2, 2, 32, false>(e, sq, labels, ap_bits, an_bits, ap_part, an_part, S,
                                   i0, j0 + jlo, 0, 0,
                                   w * 32, 0, tid, w, lane, bi == bj);
}

// ------- Kernel 3: fold scratch slots + atomic arrays, compute loss ---------
__global__ __launch_bounds__(256) void reduce_kernel(const float* __restrict__ ap_part,
                                                     const float* __restrict__ an_part,
                                                     const unsigned* __restrict__ ap_bits,
                                                     const unsigned* __restrict__ an_bits,
                                                     const int* __restrict__ labels,
                                                     float* __restrict__ acc,
                                                     unsigned* __restrict__ counter,
                                                     float* __restrict__ out) {
    const int tid = threadIdx.x;
    const int r = blockIdx.x * 256 + tid;   // 16 blocks x 256 = 4096 rows

    __shared__ int cnt[4];
    __shared__ float red[8];
    if (tid < 4) cnt[tid] = 0;
    __syncthreads();
    int local[4] = {0, 0, 0, 0};
    for (int i = tid; i < N; i += 256) local[labels[i] & 3]++;
    #pragma unroll
    for (int c = 0; c < 4; c++) if (local[c]) atomicAdd(&cnt[c], local[c]);
    __syncthreads();

    float ap = __uint_as_float(ap_bits[r]);   // split-tile contributions
    float an = __uint_as_float(an_bits[r]);
    #pragma unroll
    for (int s = 0; s < NSLOT; ++s) {
        ap = fmaxf(ap, ap_part[s * N + r]);
        an = fminf(an, an_part[s * N + r]);
    }

    float sum = 0.f, nv = 0.f;
    int l = labels[r] & 3;
    if (cnt[l] >= 2) {
        nv = 1.f;
        if (an < 3.0e38f) sum = fmaxf(ap - an + MARGIN, 0.f);
    }

    #pragma unroll
    for (int off = 32; off; off >>= 1) {
        sum += __shfl_down(sum, off, 64);
        nv  += __shfl_down(nv,  off, 64);
    }
    if ((tid & 63) == 0) { red[tid >> 6] = sum; red[4 + (tid >> 6)] = nv; }
    __syncthreads();
    if (tid == 0) {
        float bs = red[0] + red[1] + red[2] + red[3];
        float bn = red[4] + red[5] + red[6] + red[7];
        atomicAdd(&acc[0], bs);
        atomicAdd(&acc[1], bn);
        __threadfence();
        if (atomicAdd(counter, 1u) == 15u) {
            float s_ = atomicAdd(&acc[0], 0.f);   // atomic read: coherent
            float n_ = atomicAdd(&acc[1], 0.f);
            out[0] = s_ / fmaxf(n_, 1.f);
        }
    }
}

// ---------------- Launch ----------------
extern "C" void kernel_launch(void* const* d_in, const int* in_sizes, int n_in,
                              void* d_out, int out_size, void* d_ws, size_t ws_size,
                              hipStream_t stream) {
    const float* x = (const float*)d_in[0];
    const int* labels = (const int*)d_in[1];
    float* out = (float*)d_out;

    _Float16* e = (_Float16*)d_ws;
    float* sq = (float*)(e + (size_t)N * D);
    unsigned* ap_bits = (unsigned*)(sq + N);
    unsigned* an_bits = ap_bits + N;
    float* ap_part = (float*)(an_bits + N);          // NSLOT*N floats (512KB)
    float* an_part = ap_part + (size_t)NSLOT * N;    // NSLOT*N floats (512KB)
    float* acc = an_part + (size_t)NSLOT * N;        // 2 floats
    unsigned* counter = (unsigned*)(acc + 2);

    normalize_kernel<<<N / 4, 256, 0, stream>>>(x, e, sq, ap_bits, an_bits,
                                                ap_part, an_part, acc, counter);
    mine_kernel<<<NBLK, 256, 0, stream>>>(e, sq, labels, ap_bits, an_bits, ap_part, an_part);
    reduce_kernel<<<N / 256, 256, 0, stream>>>(ap_part, an_part, ap_bits, an_bits,
                                               labels, acc, counter, out);
}

// Round 3
// 116.472 us; speedup vs baseline: 1.2113x; 1.0535x over previous
//
#include <hip/hip_runtime.h>
#include <math.h>

#define N 4096
#define D 768
#define MARGIN 1.0f
#define NTILE 1056   // sum over bi=0..31 of (64 - 2*bi) 128x64 tiles
#define NKT 24       // K-steps of BK=32
#define NSLOT 64     // scratch slots per row

typedef _Float16 half8 __attribute__((ext_vector_type(8)));
typedef _Float16 half4 __attribute__((ext_vector_type(4)));
typedef float f32x4 __attribute__((ext_vector_type(4)));

__device__ __forceinline__ void gl2lds16(const void* g, void* l) {
    __builtin_amdgcn_global_load_lds((const __attribute__((address_space(1))) void*)g,
                                     (__attribute__((address_space(3))) void*)l, 16, 0, 0);
}

// counted vmcnt wait (literal must be compile-time)
template<int Nv>
__device__ __forceinline__ void wait_vm() {
    if constexpr (Nv == 0)      asm volatile("s_waitcnt vmcnt(0)" ::: "memory");
    else if constexpr (Nv == 3) asm volatile("s_waitcnt vmcnt(3)" ::: "memory");
    else                        asm volatile("s_waitcnt vmcnt(6)" ::: "memory");
}

// ---------------- Kernel 1: row L2-normalize (wave-per-row) + init ----------
__global__ __launch_bounds__(256) void normalize_kernel(const float* __restrict__ x,
                                                        _Float16* __restrict__ e,
                                                        float* __restrict__ sq,
                                                        float* __restrict__ ap_part,
                                                        float* __restrict__ an_part,
                                                        float* __restrict__ acc,
                                                        unsigned* __restrict__ counter) {
    const int tid = threadIdx.x;
    const int wave = tid >> 6, lane = tid & 63;
    const int row = blockIdx.x * 4 + wave;

    const float4* xr = (const float4*)(x + (size_t)row * D);   // 192 float4/row
    float4 f0 = xr[lane];
    float4 f1 = xr[lane + 64];
    float4 f2 = xr[lane + 128];

    float s = f0.x*f0.x + f0.y*f0.y + f0.z*f0.z + f0.w*f0.w
            + f1.x*f1.x + f1.y*f1.y + f1.z*f1.z + f1.w*f1.w
            + f2.x*f2.x + f2.y*f2.y + f2.z*f2.z + f2.w*f2.w;
    #pragma unroll
    for (int off = 1; off < 64; off <<= 1) s += __shfl_xor(s, off, 64);

    float scale = 1.0f / fmaxf(sqrtf(s), 1e-12f);

    half4* er = (half4*)(e + (size_t)row * D);
    half4 h0 = { (_Float16)(f0.x*scale), (_Float16)(f0.y*scale), (_Float16)(f0.z*scale), (_Float16)(f0.w*scale) };
    half4 h1 = { (_Float16)(f1.x*scale), (_Float16)(f1.y*scale), (_Float16)(f1.z*scale), (_Float16)(f1.w*scale) };
    half4 h2 = { (_Float16)(f2.x*scale), (_Float16)(f2.y*scale), (_Float16)(f2.z*scale), (_Float16)(f2.w*scale) };
    er[lane]       = h0;
    er[lane + 64]  = h1;
    er[lane + 128] = h2;

    if (lane == 0) sq[row] = s * scale * scale;

    // scratch init: 1024 blocks x 256 threads = 262144 = NSLOT*N exactly
    int g = blockIdx.x * 256 + tid;
    ap_part[g] = 0.0f;          // max identity (distances >= 0)
    an_part[g] = INFINITY;      // min identity

    if (blockIdx.x == 0 && tid == 0) { acc[0] = 0.f; acc[1] = 0.f; *counter = 0u; }
}

// ---------------- staging: one K-step (BK=32) of A(128 rows)+B(64 rows) ----
// 3 loads per wave per stage (uniform across waves): A = 512 granules (2/thr),
// B = 256 granules (1/thr).
__device__ __forceinline__ void stage_tile(const _Float16* __restrict__ e,
                                           int i0, int j0, int k0,
                                           unsigned short* Sb, int tid, int w) {
    #pragma unroll
    for (int p = 0; p < 2; ++p) {
        int s  = p * 256 + tid;
        int r  = s >> 2;
        int kg = (s & 3) ^ ((r >> 1) & 3);
        gl2lds16(e + (size_t)(i0 + r) * D + k0 + kg * 8,
                 (char*)Sb + (p * 256 + w * 64) * 16);
    }
    {
        int s  = tid;
        int r  = s >> 2;
        int kg = (s & 3) ^ ((r >> 1) & 3);
        gl2lds16(e + (size_t)(j0 + r) * D + k0 + kg * 8,
                 (char*)Sb + 8192 + (w * 64) * 16);
    }
}

// ------- Kernel 2: MFMA Gram + mining, 128x64 tiles, 3-buf depth-2 ---------
// LDS per buffer: A 128x32 halves (8KB, XOR-swizzled) | B 64x32 (4KB) = 12KB.
__global__ __launch_bounds__(256, 4) void mine_kernel(const _Float16* __restrict__ e,
                                                      const float* __restrict__ sq,
                                                      const int* __restrict__ labels,
                                                      float* __restrict__ ap_part,
                                                      float* __restrict__ an_part) {
    __shared__ unsigned short S[3 * 6144];   // 36KB -> 4 blocks/CU

    const int tid  = threadIdx.x;
    const int w    = tid >> 6;
    const int lane = tid & 63;
    const int ln15 = lane & 15;
    const int lq   = lane >> 4;          // 0..3
    const int wr   = w >> 1, wc = w & 1; // 2x2 wave grid
    const int wi   = wr * 64, wjL = wc * 32;

    // XCD-aware bijective swizzle (1056 = 8*132)
    const int b = (blockIdx.x & 7) * 132 + (blockIdx.x >> 3);

    // tile decode: row-panel bi (128 rows), col-panel cj (64 cols), cj >= 2*bi
    int bi = 0, rem = b;
    while (rem >= 64 - 2 * bi) { rem -= 64 - 2 * bi; ++bi; }
    const int cj = 2 * bi + rem;
    const bool diag = (rem <= 1);        // half-diagonal tiles: skip j-side
    const int i0 = bi * 128, j0 = cj * 64;

    f32x4 acc[4][2] = {};

    // prologue: stage steps 0 and 1 (depth-2 in flight, 6 loads/wave)
    stage_tile(e, i0, j0, 0,  S,        tid, w);
    stage_tile(e, i0, j0, 32, S + 6144, tid, w);

    int cur = 0, nx2 = 2;
    for (int kt = 0; kt < NKT; ++kt) {
        if (kt < NKT - 1) wait_vm<3>(); else wait_vm<0>();
        __builtin_amdgcn_s_barrier();
        __builtin_amdgcn_sched_barrier(0);

        if (kt + 2 < NKT)
            stage_tile(e, i0, j0, (kt + 2) * 32, S + nx2 * 6144, tid, w);
        __builtin_amdgcn_sched_barrier(0);

        const unsigned short* Sb = S + cur * 6144;
        half8 af[4], bf[2];
        #pragma unroll
        for (int mt = 0; mt < 4; ++mt) {
            int r  = wi + mt * 16 + ln15;
            int kx = lq ^ ((r >> 1) & 3);
            af[mt] = *(const half8*)&Sb[r * 32 + kx * 8];
        }
        #pragma unroll
        for (int nt = 0; nt < 2; ++nt) {
            int c  = wjL + nt * 16 + ln15;
            int kx = lq ^ ((c >> 1) & 3);
            bf[nt] = *(const half8*)&Sb[4096 + c * 32 + kx * 8];
        }
        __builtin_amdgcn_s_setprio(1);
        #pragma unroll
        for (int mt = 0; mt < 4; ++mt)
            #pragma unroll
            for (int nt = 0; nt < 2; ++nt)
                acc[mt][nt] = __builtin_amdgcn_mfma_f32_16x16x32_f16(af[mt], bf[nt], acc[mt][nt], 0, 0, 0);
        __builtin_amdgcn_s_setprio(0);

        cur = (cur == 2) ? 0 : cur + 1;
        nx2 = (nx2 == 2) ? 0 : nx2 + 1;
    }

    // ---------------- epilogue: dist + dual-sided batch-hard mining ----------
    float sqi[4][4]; int labi[4][4];
    #pragma unroll
    for (int mt = 0; mt < 4; ++mt)
        #pragma unroll
        for (int rg = 0; rg < 4; ++rg) {
            int i = i0 + wi + mt * 16 + lq * 4 + rg;
            sqi[mt][rg] = sq[i];
            labi[mt][rg] = labels[i];
        }
    float sqj[2]; int labj[2];
    #pragma unroll
    for (int nt = 0; nt < 2; ++nt) {
        int j = j0 + wjL + nt * 16 + ln15;
        sqj[nt] = sq[j];
        labj[nt] = labels[j];
    }

    float api[4][4], ani[4][4], apj[2], anj[2];
    #pragma unroll
    for (int mt = 0; mt < 4; ++mt)
        #pragma unroll
        for (int rg = 0; rg < 4; ++rg) { api[mt][rg] = -INFINITY; ani[mt][rg] = INFINITY; }
    #pragma unroll
    for (int nt = 0; nt < 2; ++nt) { apj[nt] = -INFINITY; anj[nt] = INFINITY; }

    #pragma unroll
    for (int nt = 0; nt < 2; ++nt) {
        int j = j0 + wjL + nt * 16 + ln15;
        #pragma unroll
        for (int mt = 0; mt < 4; ++mt)
            #pragma unroll
            for (int rg = 0; rg < 4; ++rg) {
                int i = i0 + wi + mt * 16 + lq * 4 + rg;
                float d2 = sqi[mt][rg] + sqj[nt] - 2.0f * acc[mt][nt][rg];
                float dist = sqrtf(fmaxf(d2, 0.0f) + 1e-12f);
                if (labi[mt][rg] == labj[nt]) {
                    if (i != j) {
                        api[mt][rg] = fmaxf(api[mt][rg], dist);
                        apj[nt]     = fmaxf(apj[nt], dist);
                    }
                } else {
                    ani[mt][rg] = fminf(ani[mt][rg], dist);
                    anj[nt]     = fminf(anj[nt], dist);
                }
            }
    }

    // ---- atomic-free outputs: LDS wave-merge, one plain store per (row,slot)
    // F overlays buffer 0 (last K-step computes buffer 2; buffer 0 is dead).
    float* F = (float*)S;   // 4 waves x 64 entries x 2 floats = 2KB

    // i-side: reduce over the 16 ln15-lanes, stage to LDS
    #pragma unroll
    for (int mt = 0; mt < 4; ++mt)
        #pragma unroll
        for (int rg = 0; rg < 4; ++rg) {
            float a_ = api[mt][rg], n_ = ani[mt][rg];
            #pragma unroll
            for (int off = 1; off < 16; off <<= 1) {
                a_ = fmaxf(a_, __shfl_xor(a_, off, 64));
                n_ = fminf(n_, __shfl_xor(n_, off, 64));
            }
            if (ln15 == 0) {
                int rl = mt * 16 + lq * 4 + rg;          // 0..63
                F[w * 128 + rl * 2]     = a_;
                F[w * 128 + rl * 2 + 1] = n_;
            }
        }
    __syncthreads();
    if (tid < 128) {  // merge waves sharing rows: {2wr, 2wr+1}
        int half = tid >> 6, rl = tid & 63;
        float a_ = fmaxf(F[(2 * half) * 128 + rl * 2],     F[(2 * half + 1) * 128 + rl * 2]);
        float n_ = fminf(F[(2 * half) * 128 + rl * 2 + 1], F[(2 * half + 1) * 128 + rl * 2 + 1]);
        int row = i0 + half * 64 + rl;
        ap_part[(size_t)cj * N + row] = a_;   // slot_i = cj (0..63)
        an_part[(size_t)cj * N + row] = n_;
    }

    // j-side (skip on half-diagonal tiles — i-side coverage is complete)
    if (!diag) {
        __syncthreads();
        #pragma unroll
        for (int nt = 0; nt < 2; ++nt) {
            float a_ = apj[nt], n_ = anj[nt];
            #pragma unroll
            for (int off = 16; off < 64; off <<= 1) {
                a_ = fmaxf(a_, __shfl_xor(a_, off, 64));
                n_ = fminf(n_, __shfl_xor(n_, off, 64));
            }
            if (lq == 0) {
                int jl = nt * 16 + ln15;                 // 0..31
                F[w * 128 + jl * 2]     = a_;
                F[w * 128 + jl * 2 + 1] = n_;
            }
        }
        __syncthreads();
        if (tid < 64) {   // merge waves sharing cols: {wc, wc+2}
            int wc2 = tid >> 5, jl = tid & 31;
            float a_ = fmaxf(F[wc2 * 128 + jl * 2],     F[(wc2 + 2) * 128 + jl * 2]);
            float n_ = fminf(F[wc2 * 128 + jl * 2 + 1], F[(wc2 + 2) * 128 + jl * 2 + 1]);
            int col = j0 + wc2 * 32 + jl;
            ap_part[(size_t)bi * N + col] = a_;   // slot_j = bi (0..31); disjoint from i-side slots
            an_part[(size_t)bi * N + col] = n_;
        }
    }
}

// ------- Kernel 3: fold 64 scratch slots, compute loss ---------------------
__global__ __launch_bounds__(256) void reduce_kernel(const float* __restrict__ ap_part,
                                                     const float* __restrict__ an_part,
                                                     const int* __restrict__ labels,
                                                     float* __restrict__ acc,
                                                     unsigned* __restrict__ counter,
                                                     float* __restrict__ out) {
    const int tid = threadIdx.x;
    const int rl  = tid & 63;             // row within this block's 64-row strip
    const int q   = tid >> 6;             // wave id: covers slots [q*16, q*16+16)
    const int r   = blockIdx.x * 64 + rl; // 64 blocks x 64 rows

    __shared__ int cnt[4];
    __shared__ float Fa[4][64], Fn[4][64];
    if (tid < 4) cnt[tid] = 0;
    __syncthreads();
    int local[4] = {0, 0, 0, 0};
    for (int i = tid; i < N; i += 256) local[labels[i] & 3]++;
    #pragma unroll
    for (int c = 0; c < 4; c++) if (local[c]) atomicAdd(&cnt[c], local[c]);

    float ap = 0.0f, an = INFINITY;
    #pragma unroll
    for (int s = 0; s < 16; ++s) {
        int slot = q * 16 + s;
        ap = fmaxf(ap, ap_part[(size_t)slot * N + r]);
        an = fminf(an, an_part[(size_t)slot * N + r]);
    }
    Fa[q][rl] = ap; Fn[q][rl] = an;
    __syncthreads();

    if (tid < 64) {
        float a_ = fmaxf(fmaxf(Fa[0][tid], Fa[1][tid]), fmaxf(Fa[2][tid], Fa[3][tid]));
        float n_ = fminf(fminf(Fn[0][tid], Fn[1][tid]), fminf(Fn[2][tid], Fn[3][tid]));
        int row = blockIdx.x * 64 + tid;
        int l = labels[row] & 3;
        float sum = 0.f, nv = 0.f;
        if (cnt[l] >= 2) {
            nv = 1.f;
            if (n_ < 3.0e38f) sum = fmaxf(a_ - n_ + MARGIN, 0.f);
        }
        #pragma unroll
        for (int off = 32; off; off >>= 1) {
            sum += __shfl_down(sum, off, 64);
            nv  += __shfl_down(nv,  off, 64);
        }
        if (tid == 0) {
            atomicAdd(&acc[0], sum);
            atomicAdd(&acc[1], nv);
            __threadfence();
            if (atomicAdd(counter, 1u) == 63u) {
                float s_ = atomicAdd(&acc[0], 0.f);   // atomic read: coherent
                float nn = atomicAdd(&acc[1], 0.f);
                out[0] = s_ / fmaxf(nn, 1.f);
            }
        }
    }
}

// ---------------- Launch ----------------
extern "C" void kernel_launch(void* const* d_in, const int* in_sizes, int n_in,
                              void* d_out, int out_size, void* d_ws, size_t ws_size,
                              hipStream_t stream) {
    const float* x = (const float*)d_in[0];
    const int* labels = (const int*)d_in[1];
    float* out = (float*)d_out;

    _Float16* e = (_Float16*)d_ws;
    float* sq = (float*)(e + (size_t)N * D);
    float* ap_part = sq + N;                         // NSLOT*N floats (1MB)
    float* an_part = ap_part + (size_t)NSLOT * N;    // NSLOT*N floats (1MB)
    float* acc = an_part + (size_t)NSLOT * N;        // 2 floats
    unsigned* counter = (unsigned*)(acc + 2);

    normalize_kernel<<<N / 4, 256, 0, stream>>>(x, e, sq, ap_part, an_part, acc, counter);
    mine_kernel<<<NTILE, 256, 0, stream>>>(e, sq, labels, ap_part, an_part);
    reduce_kernel<<<N / 64, 256, 0, stream>>>(ap_part, an_part, labels, acc, counter, out);
}